// Round 15
// baseline (174.253 us; speedup 1.0000x reference)
//
#include <hip/hip_runtime.h>

#define B_ 8
#define N_ 4096
#define C_ 512

typedef _Float16 f16;
typedef __attribute__((ext_vector_type(8))) _Float16 f16x8;
typedef __attribute__((ext_vector_type(4))) _Float16 f16x4;
typedef __attribute__((ext_vector_type(4))) float f32x4;

// global -> LDS async copy, 16B per lane. LDS dest must be wave-uniform base;
// lane adds l*16 in hardware. Global src is per-lane.
#define GLL16(gsrc, ldst)                                                      \
  __builtin_amdgcn_global_load_lds(                                            \
      (const __attribute__((address_space(1))) void*)(gsrc),                   \
      (__attribute__((address_space(3))) void*)(ldst), 16, 0, 0)

__device__ __forceinline__ int xcd_remap(int bid, int nwg) {
  // nwg % 8 == 0 for all our grids -> bijective chunked remap (T1)
  return (bid & 7) * (nwg >> 3) + (bid >> 3);
}

// ---------------------------------------------------------------------------
// 128x128 / BK=32 / 256-thread (4 waves 2x2, per-wave 64x64) 2-phase mainloop.
// LDS = 2 bufs x (A 8KB + B 8KB) = 32KB -> 4 blocks/CU at VGPR<=64
// (launch_bounds(256,4); r9 measured VGPR=64, Occupancy 37%).
// CORRECTED swizzle vs r9 (r9's (row&3) gave 4-way -> 6.3M conflicts):
// bank(row,slot) = (16*row + 4*slot) mod 32; a wave's b128 read fixes slot g
// and parity(row) -> 8 lanes/class unswizzled. slot' = slot ^ ((row>>1)&3)
// spreads the 8 same-parity rows over all 4 slots = 2 lanes/class = 2-way
// residual (free, m136). Read element-XOR ((r15>>1)&3)<<3 is lane-constant:
// actual row = wr*64 + m*16 + r15 and (row>>1)&3 == (r15>>1)&3 (offsets are
// multiples of 8). GLL16 dest LINEAR; source col byte-XOR ((row>>1)&3)<<4.
// Stage dest: chunk id = ld*256 + wv*64 + lane -> wave base = ld*2048 +
// wv*512 elements... NOTE tile = 4096 elem: base = (t&1)*4096 + wv*512,
// chunks at +ld*2048 (r9 arithmetic, verified correct there).
// ---------------------------------------------------------------------------
template <int LDA2, int LDB2, int NT>
__device__ __forceinline__ void mainloop32(const char* __restrict__ Agb,
                                           const char* __restrict__ Bgb,
                                           f16* Als, f16* Bls,
                                           f32x4 (&acc)[4][4]) {
  const int tid = threadIdx.x;
  const int lane = tid & 63;
  const int wv = tid >> 6;
  const int wr = wv >> 1;   // M half (0..1)
  const int wc = wv & 1;    // N half (0..1)

  // fragment read geometry (f16 elements), 32 elem = 64B per row
  const int r15 = lane & 15;
  const int kc8 = (lane >> 4) << 3;        // k slot base: 0,8,16,24
  const int swz = ((r15 >> 1) & 3) << 3;   // CORRECTED slot XOR
  const int kx = kc8 ^ swz;
  const int awbase = (wr * 64 + r15) * 32;
  const int bwbase = (wc * 64 + r15) * 32;

  // stage source offsets: LDS dest linear; source col inverse-swizzled
  int rowl[2], colb[2];
#pragma unroll
  for (int ld = 0; ld < 2; ++ld) {
    const int doff = (ld * 256 + tid) * 16;  // dest byte within 8KB tile
    rowl[ld] = doff >> 6;
    colb[ld] = (doff & 63) ^ (((rowl[ld] >> 1) & 3) << 4);
  }

  auto stage = [&](int t) {
    if (t >= NT) return;
    f16* la = Als + (t & 1) * 4096 + wv * 512;  // wave base; lane*16B in HW
    f16* lb = Bls + (t & 1) * 4096 + wv * 512;
#pragma unroll
    for (int ld = 0; ld < 2; ++ld) {
      GLL16(Agb + (size_t)rowl[ld] * LDA2 + (size_t)t * 64 + colb[ld],
            la + ld * 2048);
      GLL16(Bgb + (size_t)rowl[ld] * LDB2 + (size_t)t * 64 + colb[ld],
            lb + ld * 2048);
    }
  };

  stage(0);
  __syncthreads();

  for (int T = 0; T < NT; ++T) {
    stage(T + 1);  // other buffer; its readers (T-1) drained at prev barrier
    const f16* Ab = Als + (T & 1) * 4096;
    const f16* Bb = Bls + (T & 1) * 4096;
    f16x8 af[4], bf[4];
#pragma unroll
    for (int m = 0; m < 4; ++m)
      af[m] = *(const f16x8*)(Ab + awbase + m * 512 + kx);
#pragma unroll
    for (int n = 0; n < 4; ++n)
      bf[n] = *(const f16x8*)(Bb + bwbase + n * 512 + kx);
#pragma unroll
    for (int m = 0; m < 4; ++m)
#pragma unroll
      for (int n = 0; n < 4; ++n)
        acc[m][n] = __builtin_amdgcn_mfma_f32_16x16x32_f16(af[m], bf[n],
                                                           acc[m][n], 0, 0, 0);
    __syncthreads();  // vmcnt(0)+lgkmcnt(0) drain; 3 other blocks fill stall
  }
}

#define ZERO_ACC(acc)                                                          \
  f32x4 acc[4][4];                                                             \
  _Pragma("unroll") for (int zi = 0; zi < 4; ++zi)                             \
      _Pragma("unroll") for (int zj = 0; zj < 4; ++zj) {                       \
    f32x4 z = {0.f, 0.f, 0.f, 0.f};                                            \
    acc[zi][zj] = z;                                                           \
  }

// --------------------------- fused prep kernel -----------------------------
// bid [0,16384): x f32 -> f16 (float4/thread)
// bid [16384,19456): Wqkv [512][1536] -> wqkvt [1536][512]
// bid [19456,20480): Wo [512][512] -> wot [512][512] transposed
__global__ void __launch_bounds__(256)
    k_prep(const float* __restrict__ x, const float* __restrict__ Wqkv,
           const float* __restrict__ Wo, f16* __restrict__ x16,
           f16* __restrict__ wqkvt, f16* __restrict__ wot) {
  const int bid = blockIdx.x;
  if (bid < 16384) {
    const int i = bid * 256 + threadIdx.x;
    float4 v = ((const float4*)x)[i];
    f16x4 h = {(f16)v.x, (f16)v.y, (f16)v.z, (f16)v.w};
    ((f16x4*)x16)[i] = h;
  } else if (bid < 19456) {
    const int idx = (bid - 16384) * 256 + threadIdx.x;  // over 1536*512
    const int n = idx >> 9, c = idx & 511;
    wqkvt[idx] = (f16)Wqkv[(size_t)c * 1536 + n];
  } else {
    const int idx = (bid - 19456) * 256 + threadIdx.x;  // over 512*512
    const int n = idx >> 9, c = idx & 511;
    wot[idx] = (f16)Wo[(size_t)c * 512 + n];
  }
}

// --------------------------- GEMM kernels ----------------------------------
// qkv = relu(x @ Wqkv + b); writes q^T,k^T [C][N] f16, v [N][C] f16
// grid: 3072 = 12 col-tiles x 256 row-tiles; NT=16
__global__ void __launch_bounds__(256, 4)
    k_gemm_qkv(const f16* __restrict__ x16, const f16* __restrict__ wqkvt,
               const float* __restrict__ bqkv, f16* __restrict__ q_t,
               f16* __restrict__ k_t, f16* __restrict__ v16) {
  __shared__ alignas(16) f16 Als[2 * 4096];
  __shared__ alignas(16) f16 Bls[2 * 4096];
  const int l = xcd_remap(blockIdx.x, 3072);
  const int bx = l % 12;           // weight col tile
  const int my = l / 12;           // row tile over 32768 rows
  const char* Agb = (const char*)(x16 + (size_t)my * 128 * C_);
  const char* Bgb = (const char*)(wqkvt + (size_t)bx * 128 * C_);
  ZERO_ACC(acc);
  mainloop32<C_ * 2, C_ * 2, 16>(Agb, Bgb, Als, Bls, acc);

  const int lane = threadIdx.x & 63, wv = threadIdx.x >> 6;
  const int wr = wv >> 1, wc = wv & 1;
  const int sec = bx >> 2;  // 0=q 1=k 2=v, uniform per block (128 | 512)
  const int colbase = bx * 128 + wc * 64;
  const int rowbase = my * 128 + wr * 64;  // global row in [0,32768)
  const int b = rowbase >> 12;             // uniform per block
#pragma unroll
  for (int n = 0; n < 4; ++n) {
    const int col = colbase + n * 16 + (lane & 15);
    const int cch = col & 511;
    const float bias = bqkv[col];
#pragma unroll
    for (int m = 0; m < 4; ++m) {
      const int rg = rowbase + m * 16 + ((lane >> 4) << 2);  // global row
      const int nloc = rg & 4095;
      f32x4 a = acc[m][n];
      f16x4 h = {(f16)fmaxf(a[0] + bias, 0.f), (f16)fmaxf(a[1] + bias, 0.f),
                 (f16)fmaxf(a[2] + bias, 0.f), (f16)fmaxf(a[3] + bias, 0.f)};
      if (sec == 0) {
        *(f16x4*)(q_t + ((size_t)b * C_ + cch) * N_ + nloc) = h;
      } else if (sec == 1) {
        *(f16x4*)(k_t + ((size_t)b * C_ + cch) * N_ + nloc) = h;
      } else {
        f16* dst = v16 + (size_t)rg * C_ + cch;
        dst[0] = h[0];
        dst[C_] = h[1];
        dst[2 * C_] = h[2];
        dst[3 * C_] = h[3];
      }
    }
  }
}

// scores partial: spart[sp][b][c][d] = sum_{n in split sp} q[n,c]k[n,d], f16
// split-K = 4 (1024 n per split): grid 512 = 4 x 4 x (8 batch * 4 splits),
// NT=32
__global__ void __launch_bounds__(256, 4)
    k_gemm_scores(const f16* __restrict__ q_t, const f16* __restrict__ k_t,
                  f16* __restrict__ spart) {
  __shared__ alignas(16) f16 Als[2 * 4096];
  __shared__ alignas(16) f16 Bls[2 * 4096];
  const int l = xcd_remap(blockIdx.x, 512);
  const int bx = l & 3;
  const int by = (l >> 2) & 3;
  const int z = l >> 4;                 // in [0,32)
  const int b = z >> 2, sp = z & 3;
  const char* Agb = (const char*)(q_t + (size_t)b * C_ * N_ +
                                  (size_t)(by * 128) * N_ + sp * 1024);
  const char* Bgb = (const char*)(k_t + (size_t)b * C_ * N_ +
                                  (size_t)(bx * 128) * N_ + sp * 1024);
  ZERO_ACC(acc);
  mainloop32<N_ * 2, N_ * 2, 32>(Agb, Bgb, Als, Bls, acc);

  const int lane = threadIdx.x & 63, wv = threadIdx.x >> 6;
  const int wr = wv >> 1, wc = wv & 1;
  f16* base = spart + (size_t)(sp * B_ + b) * C_ * C_;
#pragma unroll
  for (int n = 0; n < 4; ++n) {
    const int d = bx * 128 + wc * 64 + n * 16 + (lane & 15);
#pragma unroll
    for (int m = 0; m < 4; ++m) {
      const int c0 = by * 128 + wr * 64 + m * 16 + ((lane >> 4) << 2);
#pragma unroll
      for (int r = 0; r < 4; ++r)
        base[(size_t)(c0 + r) * C_ + d] = (f16)acc[m][n][r];
    }
  }
}

// attn = softmax(sum_sp(spart)*scale, axis=-1) * adj  -> f16
// wave-per-row: 4096 rows -> grid 1024 x 256thr (4 rows/block)
__global__ void __launch_bounds__(256)
    k_softmax_gate(const f16* __restrict__ spart,
                   const float* __restrict__ adj, f16* __restrict__ attn) {
  const int wv = threadIdx.x >> 6, lane = threadIdx.x & 63;
  const int row = blockIdx.x * 4 + wv;         // (b*512+c) in [0,4096)
  const size_t ro = (size_t)row * 512;
  const int off = lane * 8;

  float s[8] = {0.f, 0.f, 0.f, 0.f, 0.f, 0.f, 0.f, 0.f};
#pragma unroll
  for (int sp = 0; sp < 4; ++sp) {
    f16x8 v = *(const f16x8*)(spart + (size_t)sp * (B_ * C_ * C_) + ro + off);
#pragma unroll
    for (int i = 0; i < 8; ++i) s[i] += (float)v[i];
  }
  const float scale = 0.044194173824159216f;  // 1/sqrt(512)
  float mx = -1e30f;
#pragma unroll
  for (int i = 0; i < 8; ++i) {
    s[i] *= scale;
    mx = fmaxf(mx, s[i]);
  }
#pragma unroll
  for (int d = 32; d > 0; d >>= 1) mx = fmaxf(mx, __shfl_xor(mx, d, 64));
  float e[8], sum = 0.f;
#pragma unroll
  for (int i = 0; i < 8; ++i) {
    e[i] = __expf(s[i] - mx);
    sum += e[i];
  }
#pragma unroll
  for (int d = 32; d > 0; d >>= 1) sum += __shfl_xor(sum, d, 64);
  const float inv = 1.0f / sum;
  const float4 a0 = *(const float4*)(adj + ro + off);
  const float4 a1 = *(const float4*)(adj + ro + off + 4);
  f16x8 o;
  o[0] = (f16)(e[0] * inv * a0.x); o[1] = (f16)(e[1] * inv * a0.y);
  o[2] = (f16)(e[2] * inv * a0.z); o[3] = (f16)(e[3] * inv * a0.w);
  o[4] = (f16)(e[4] * inv * a1.x); o[5] = (f16)(e[5] * inv * a1.y);
  o[6] = (f16)(e[6] * inv * a1.z); o[7] = (f16)(e[7] * inv * a1.w);
  *(f16x8*)(attn + ro + off) = o;
}

// M^T[e][c] = sum_d attn[c][d] * Wo[d][e]
// grid: 128 = 4 e-tiles x 4 c-tiles x 8 batch, NT=16
__global__ void __launch_bounds__(256, 4)
    k_gemm_m(const f16* __restrict__ attn, const f16* __restrict__ wot,
             f16* __restrict__ mt) {
  __shared__ alignas(16) f16 Als[2 * 4096];
  __shared__ alignas(16) f16 Bls[2 * 4096];
  const int l = xcd_remap(blockIdx.x, 128);
  const int bx = l & 3;
  const int by = (l >> 2) & 3;
  const int b = l >> 4;
  const char* Agb = (const char*)(attn + (size_t)b * C_ * C_ +
                                  (size_t)(by * 128) * C_);
  const char* Bgb = (const char*)(wot + (size_t)(bx * 128) * C_);
  ZERO_ACC(acc);
  mainloop32<C_ * 2, C_ * 2, 16>(Agb, Bgb, Als, Bls, acc);

  const int lane = threadIdx.x & 63, wv = threadIdx.x >> 6;
  const int wr = wv >> 1, wc = wv & 1;
  f16* base = mt + (size_t)b * C_ * C_;
  const int colbase = bx * 128 + wc * 64;
  const int rowbase = by * 128 + wr * 64;
#pragma unroll
  for (int j = 0; j < 4; ++j) {
    const int e = colbase + j * 16 + (lane & 15);
#pragma unroll
    for (int i = 0; i < 4; ++i) {
      const int c0 = rowbase + i * 16 + ((lane >> 4) << 2);
      f32x4 a = acc[i][j];
      f16x4 h = {(f16)a[0], (f16)a[1], (f16)a[2], (f16)a[3]};
      *(f16x4*)(base + (size_t)e * C_ + c0) = h;  // transposed store
    }
  }
}

// out[n][e] = sum_c v[n][c] * M[c][e] + bo[e]   (fp32 out)
// grid: 1024 = 4 col tiles x 256 row tiles, NT=16
__global__ void __launch_bounds__(256, 4)
    k_gemm_out(const f16* __restrict__ v16, const f16* __restrict__ mt,
               const float* __restrict__ bo, float* __restrict__ out) {
  __shared__ alignas(16) f16 Als[2 * 4096];
  __shared__ alignas(16) f16 Bls[2 * 4096];
  const int l = xcd_remap(blockIdx.x, 1024);
  const int bx = l & 3;
  const int my = l >> 2;                   // row tile over 32768 rows
  const int b = (my * 128) >> 12;          // uniform per block
  const char* Agb = (const char*)(v16 + (size_t)my * 128 * C_);
  const char* Bgb = (const char*)(mt + (size_t)b * C_ * C_ +
                                  (size_t)(bx * 128) * C_);
  ZERO_ACC(acc);
  mainloop32<C_ * 2, C_ * 2, 16>(Agb, Bgb, Als, Bls, acc);

  const int lane = threadIdx.x & 63, wv = threadIdx.x >> 6;
  const int wr = wv >> 1, wc = wv & 1;
#pragma unroll
  for (int n = 0; n < 4; ++n) {
    const int e = bx * 128 + wc * 64 + n * 16 + (lane & 15);
    const float bias = bo[e];
#pragma unroll
    for (int m = 0; m < 4; ++m) {
      const int rg = my * 128 + wr * 64 + m * 16 + ((lane >> 4) << 2);
#pragma unroll
      for (int r = 0; r < 4; ++r)
        out[(size_t)(rg + r) * C_ + e] = acc[m][n][r] + bias;
    }
  }
}

// ---------------------------------------------------------------------------
extern "C" void kernel_launch(void* const* d_in, const int* in_sizes, int n_in,
                              void* d_out, int out_size, void* d_ws,
                              size_t ws_size, hipStream_t stream) {
  const float* x = (const float*)d_in[0];
  const float* adj = (const float*)d_in[1];
  const float* Wqkv = (const float*)d_in[2];
  const float* bqkv = (const float*)d_in[3];
  const float* Wo = (const float*)d_in[4];
  const float* bo = (const float*)d_in[5];
  float* out = (float*)d_out;

  char* ws = (char*)d_ws;
  size_t off = 0;
  auto carve = [&](size_t bytes) -> char* {
    char* p = ws + off;
    off += (bytes + 255) & ~(size_t)255;
    return p;
  };
  f16* x16 = (f16*)carve((size_t)B_ * N_ * C_ * 2);       // 33.6 MB
  f16* wqkvt = (f16*)carve((size_t)3 * C_ * C_ * 2);      // 1.6 MB
  f16* wot = (f16*)carve((size_t)C_ * C_ * 2);            // 0.5 MB
  f16* q_t = (f16*)carve((size_t)B_ * C_ * N_ * 2);       // 33.6 MB
  f16* k_t = (f16*)carve((size_t)B_ * C_ * N_ * 2);       // 33.6 MB
  f16* v16 = (f16*)carve((size_t)B_ * N_ * C_ * 2);       // 33.6 MB
  // aliases over dead buffers (stream order guarantees liveness separation)
  f16* spart = x16;             // 4 splits x 8 x 512 x 512 f16 = 16.8 MB
  f16* attn16 = k_t;            // 4.2 MB, k_t dead after scores
  f16* mt16 = q_t;              // 4.2 MB, q_t dead after scores

  k_prep<<<20480, 256, 0, stream>>>(x, Wqkv, Wo, x16, wqkvt, wot);
  k_gemm_qkv<<<3072, 256, 0, stream>>>(x16, wqkvt, bqkv, q_t, k_t, v16);
  k_gemm_scores<<<512, 256, 0, stream>>>(q_t, k_t, spart);
  k_softmax_gate<<<1024, 256, 0, stream>>>(spart, adj, attn16);
  k_gemm_m<<<128, 256, 0, stream>>>(attn16, wot, mt16);
  k_gemm_out<<<1024, 256, 0, stream>>>(v16, mt16, bo, out);
}

// Round 16
// 165.540 us; speedup vs baseline: 1.0526x; 1.0526x over previous
//
#include <hip/hip_runtime.h>

#define B_ 8
#define N_ 4096
#define C_ 512

typedef _Float16 f16;
typedef __attribute__((ext_vector_type(8))) _Float16 f16x8;
typedef __attribute__((ext_vector_type(4))) _Float16 f16x4;
typedef __attribute__((ext_vector_type(4))) float f32x4;

// global -> LDS async copy, 16B per lane. LDS dest must be wave-uniform base;
// lane adds l*16 in hardware. Global src is per-lane.
#define GLL16(gsrc, ldst)                                                      \
  __builtin_amdgcn_global_load_lds(                                            \
      (const __attribute__((address_space(1))) void*)(gsrc),                   \
      (__attribute__((address_space(3))) void*)(ldst), 16, 0, 0)

__device__ __forceinline__ int xcd_remap(int bid, int nwg) {
  // nwg % 8 == 0 for all our grids -> bijective chunked remap (T1)
  return (bid & 7) * (nwg >> 3) + (bid >> 3);
}

// ---------------------------------------------------------------------------
// 128x128 / BK=64 / 256-thread (4 waves 2x2, per-wave 64x64) 2-phase mainloop.
// FINAL VERIFIED config (r7/r10/r12/r14): conflicts=0, qkv ~78us, 2 blocks/CU.
// LDS = 2 bufs x (A16K+B16K) = 64KB. Swizzle: element (row,k) at
// k ^ ((row&7)<<3); 128B rows -> rows 0-7 hit 8 distinct 16B slots = all 32
// banks; r vs r+8 2-way (free, m136). global_load_lds dest LINEAR, source col
// inverse-swizzled. Stage dest: chunk id = ld*256 + wv*64 + lane -> wave base
// = ld*2048 + wv*512 elements (r6 lesson).
// Falsified alternatives (counter-verified): 8-phase counted-vmcnt (r2/r4/r5:
// no gain at NT=8), 4 blocks/CU BK=32 conflict-free (r15: 84.5us > 78),
// reg-staged x-fusion (r11: 133us), persistent-M/K (r3/r13: regress).
// ---------------------------------------------------------------------------
template <int LDA2, int LDB2, int NT>
__device__ __forceinline__ void mainloop2(const char* __restrict__ Agb,
                                          const char* __restrict__ Bgb,
                                          f16* Als, f16* Bls,
                                          f32x4 (&acc)[4][4]) {
  const int tid = threadIdx.x;
  const int lane = tid & 63;
  const int wv = tid >> 6;
  const int wr = wv >> 1;   // M half (0..1)
  const int wc = wv & 1;    // N half (0..1)

  // fragment read geometry (f16 elements)
  const int r15 = lane & 15;
  const int kc8 = (lane >> 4) << 3;     // k chunk base: 0,8,16,24
  const int swz = (r15 & 7) << 3;       // element XOR for this lane's row
  const int k0x = kc8 ^ swz;            // k-half 0
  const int k1x = (kc8 + 32) ^ swz;     // k-half 1
  const int awbase = (wr * 64 + r15) * 64;
  const int bwbase = (wc * 64 + r15) * 64;

  // stage source offsets: LDS dest linear; source col inverse-swizzled.
  int rowl[4], colb[4];
#pragma unroll
  for (int ld = 0; ld < 4; ++ld) {
    const int doff = (ld * 256 + tid) * 16;  // dest byte within tile
    rowl[ld] = doff >> 7;
    colb[ld] = (doff & 127) ^ ((rowl[ld] & 7) << 4);
  }

  auto stage = [&](int t) {
    if (t >= NT) return;
    f16* la = Als + (t & 1) * 8192 + wv * 512;  // wave base; lane*16B in HW
    f16* lb = Bls + (t & 1) * 8192 + wv * 512;
#pragma unroll
    for (int ld = 0; ld < 4; ++ld) {
      GLL16(Agb + (size_t)rowl[ld] * LDA2 + (size_t)t * 128 + colb[ld],
            la + ld * 2048);
      GLL16(Bgb + (size_t)rowl[ld] * LDB2 + (size_t)t * 128 + colb[ld],
            lb + ld * 2048);
    }
  };

  stage(0);
  __syncthreads();

  for (int T = 0; T < NT; ++T) {
    stage(T + 1);  // other buffer; its readers (T-1) drained at prev barrier
    const f16* Ab = Als + (T & 1) * 8192;
    const f16* Bb = Bls + (T & 1) * 8192;
    f16x8 af[4][2], bf[4][2];
#pragma unroll
    for (int m = 0; m < 4; ++m) {
      af[m][0] = *(const f16x8*)(Ab + awbase + m * 1024 + k0x);
      af[m][1] = *(const f16x8*)(Ab + awbase + m * 1024 + k1x);
    }
#pragma unroll
    for (int n = 0; n < 4; ++n) {
      bf[n][0] = *(const f16x8*)(Bb + bwbase + n * 1024 + k0x);
      bf[n][1] = *(const f16x8*)(Bb + bwbase + n * 1024 + k1x);
    }
#pragma unroll
    for (int s = 0; s < 2; ++s)
#pragma unroll
      for (int m = 0; m < 4; ++m)
#pragma unroll
        for (int n = 0; n < 4; ++n)
          acc[m][n] = __builtin_amdgcn_mfma_f32_16x16x32_f16(
              af[m][s], bf[n][s], acc[m][n], 0, 0, 0);
    __syncthreads();  // vmcnt(0)+lgkmcnt(0) drain; other block fills stall
  }
}

#define ZERO_ACC(acc)                                                          \
  f32x4 acc[4][4];                                                             \
  _Pragma("unroll") for (int zi = 0; zi < 4; ++zi)                             \
      _Pragma("unroll") for (int zj = 0; zj < 4; ++zj) {                       \
    f32x4 z = {0.f, 0.f, 0.f, 0.f};                                            \
    acc[zi][zj] = z;                                                           \
  }

// --------------------------- fused prep kernel -----------------------------
// bid [0,16384): x f32 -> f16 (float4/thread)
// bid [16384,19456): Wqkv [512][1536] -> wqkvt [1536][512]
// bid [19456,20480): Wo [512][512] -> wot [512][512] transposed
__global__ void __launch_bounds__(256)
    k_prep(const float* __restrict__ x, const float* __restrict__ Wqkv,
           const float* __restrict__ Wo, f16* __restrict__ x16,
           f16* __restrict__ wqkvt, f16* __restrict__ wot) {
  const int bid = blockIdx.x;
  if (bid < 16384) {
    const int i = bid * 256 + threadIdx.x;
    float4 v = ((const float4*)x)[i];
    f16x4 h = {(f16)v.x, (f16)v.y, (f16)v.z, (f16)v.w};
    ((f16x4*)x16)[i] = h;
  } else if (bid < 19456) {
    const int idx = (bid - 16384) * 256 + threadIdx.x;  // over 1536*512
    const int n = idx >> 9, c = idx & 511;
    wqkvt[idx] = (f16)Wqkv[(size_t)c * 1536 + n];
  } else {
    const int idx = (bid - 19456) * 256 + threadIdx.x;  // over 512*512
    const int n = idx >> 9, c = idx & 511;
    wot[idx] = (f16)Wo[(size_t)c * 512 + n];
  }
}

// --------------------------- GEMM kernels ----------------------------------
// qkv = relu(x @ Wqkv + b); writes q^T,k^T [C][N] f16, v [N][C] f16
// grid: 3072 = 12 col-tiles x 256 row-tiles; consecutive l share the x panel.
__global__ void __launch_bounds__(256, 2)
    k_gemm_qkv(const f16* __restrict__ x16, const f16* __restrict__ wqkvt,
               const float* __restrict__ bqkv, f16* __restrict__ q_t,
               f16* __restrict__ k_t, f16* __restrict__ v16) {
  __shared__ alignas(16) f16 Als[2 * 8192];
  __shared__ alignas(16) f16 Bls[2 * 8192];
  const int l = xcd_remap(blockIdx.x, 3072);
  const int bx = l % 12;           // weight col tile
  const int my = l / 12;           // row tile over 32768 rows
  const char* Agb = (const char*)(x16 + (size_t)my * 128 * C_);
  const char* Bgb = (const char*)(wqkvt + (size_t)bx * 128 * C_);
  ZERO_ACC(acc);
  mainloop2<C_ * 2, C_ * 2, C_ / 64>(Agb, Bgb, Als, Bls, acc);

  const int lane = threadIdx.x & 63, wv = threadIdx.x >> 6;
  const int wr = wv >> 1, wc = wv & 1;
  const int sec = bx >> 2;  // 0=q 1=k 2=v, uniform per block (128 | 512)
  const int colbase = bx * 128 + wc * 64;
  const int rowbase = my * 128 + wr * 64;  // global row in [0,32768)
  const int b = rowbase >> 12;             // uniform per block
#pragma unroll
  for (int n = 0; n < 4; ++n) {
    const int col = colbase + n * 16 + (lane & 15);
    const int cch = col & 511;
    const float bias = bqkv[col];
#pragma unroll
    for (int m = 0; m < 4; ++m) {
      const int rg = rowbase + m * 16 + ((lane >> 4) << 2);  // global row
      const int nloc = rg & 4095;
      f32x4 a = acc[m][n];
      f16x4 h = {(f16)fmaxf(a[0] + bias, 0.f), (f16)fmaxf(a[1] + bias, 0.f),
                 (f16)fmaxf(a[2] + bias, 0.f), (f16)fmaxf(a[3] + bias, 0.f)};
      if (sec == 0) {
        *(f16x4*)(q_t + ((size_t)b * C_ + cch) * N_ + nloc) = h;
      } else if (sec == 1) {
        *(f16x4*)(k_t + ((size_t)b * C_ + cch) * N_ + nloc) = h;
      } else {
        f16* dst = v16 + (size_t)rg * C_ + cch;
        dst[0] = h[0];
        dst[C_] = h[1];
        dst[2 * C_] = h[2];
        dst[3 * C_] = h[3];
      }
    }
  }
}

// scores partial: spart[sp][b][c][d] = sum_{n in split sp} q[n,c]k[n,d], f16
// split-K = 4 (1024 n per split): grid 512 = 4 x 4 x (8 batch * 4 splits),
// NT=16. One full round at 2 blocks/CU; spart traffic halves vs 8-split.
__global__ void __launch_bounds__(256, 2)
    k_gemm_scores(const f16* __restrict__ q_t, const f16* __restrict__ k_t,
                  f16* __restrict__ spart) {
  __shared__ alignas(16) f16 Als[2 * 8192];
  __shared__ alignas(16) f16 Bls[2 * 8192];
  const int l = xcd_remap(blockIdx.x, 512);
  const int bx = l & 3;
  const int by = (l >> 2) & 3;
  const int z = l >> 4;                 // in [0,32)
  const int b = z >> 2, sp = z & 3;
  const char* Agb = (const char*)(q_t + (size_t)b * C_ * N_ +
                                  (size_t)(by * 128) * N_ + sp * 1024);
  const char* Bgb = (const char*)(k_t + (size_t)b * C_ * N_ +
                                  (size_t)(bx * 128) * N_ + sp * 1024);
  ZERO_ACC(acc);
  mainloop2<N_ * 2, N_ * 2, 16>(Agb, Bgb, Als, Bls, acc);

  const int lane = threadIdx.x & 63, wv = threadIdx.x >> 6;
  const int wr = wv >> 1, wc = wv & 1;
  f16* base = spart + (size_t)(sp * B_ + b) * C_ * C_;
#pragma unroll
  for (int n = 0; n < 4; ++n) {
    const int d = bx * 128 + wc * 64 + n * 16 + (lane & 15);
#pragma unroll
    for (int m = 0; m < 4; ++m) {
      const int c0 = by * 128 + wr * 64 + m * 16 + ((lane >> 4) << 2);
#pragma unroll
      for (int r = 0; r < 4; ++r)
        base[(size_t)(c0 + r) * C_ + d] = (f16)acc[m][n][r];
    }
  }
}

// attn = softmax(sum_sp(spart)*scale, axis=-1) * adj  -> f16
// wave-per-row: 4096 rows -> grid 1024 x 256thr (4 rows/block)
__global__ void __launch_bounds__(256)
    k_softmax_gate(const f16* __restrict__ spart,
                   const float* __restrict__ adj, f16* __restrict__ attn) {
  const int wv = threadIdx.x >> 6, lane = threadIdx.x & 63;
  const int row = blockIdx.x * 4 + wv;         // (b*512+c) in [0,4096)
  const size_t ro = (size_t)row * 512;
  const int off = lane * 8;

  float s[8] = {0.f, 0.f, 0.f, 0.f, 0.f, 0.f, 0.f, 0.f};
#pragma unroll
  for (int sp = 0; sp < 4; ++sp) {
    f16x8 v = *(const f16x8*)(spart + (size_t)sp * (B_ * C_ * C_) + ro + off);
#pragma unroll
    for (int i = 0; i < 8; ++i) s[i] += (float)v[i];
  }
  const float scale = 0.044194173824159216f;  // 1/sqrt(512)
  float mx = -1e30f;
#pragma unroll
  for (int i = 0; i < 8; ++i) {
    s[i] *= scale;
    mx = fmaxf(mx, s[i]);
  }
#pragma unroll
  for (int d = 32; d > 0; d >>= 1) mx = fmaxf(mx, __shfl_xor(mx, d, 64));
  float e[8], sum = 0.f;
#pragma unroll
  for (int i = 0; i < 8; ++i) {
    e[i] = __expf(s[i] - mx);
    sum += e[i];
  }
#pragma unroll
  for (int d = 32; d > 0; d >>= 1) sum += __shfl_xor(sum, d, 64);
  const float inv = 1.0f / sum;
  const float4 a0 = *(const float4*)(adj + ro + off);
  const float4 a1 = *(const float4*)(adj + ro + off + 4);
  f16x8 o;
  o[0] = (f16)(e[0] * inv * a0.x); o[1] = (f16)(e[1] * inv * a0.y);
  o[2] = (f16)(e[2] * inv * a0.z); o[3] = (f16)(e[3] * inv * a0.w);
  o[4] = (f16)(e[4] * inv * a1.x); o[5] = (f16)(e[5] * inv * a1.y);
  o[6] = (f16)(e[6] * inv * a1.z); o[7] = (f16)(e[7] * inv * a1.w);
  *(f16x8*)(attn + ro + off) = o;
}

// M^T[e][c] = sum_d attn[c][d] * Wo[d][e]
// grid: 128 = 4 e-tiles x 4 c-tiles x 8 batch, NT=8
__global__ void __launch_bounds__(256, 2)
    k_gemm_m(const f16* __restrict__ attn, const f16* __restrict__ wot,
             f16* __restrict__ mt) {
  __shared__ alignas(16) f16 Als[2 * 8192];
  __shared__ alignas(16) f16 Bls[2 * 8192];
  const int l = xcd_remap(blockIdx.x, 128);
  const int bx = l & 3;
  const int by = (l >> 2) & 3;
  const int b = l >> 4;
  const char* Agb = (const char*)(attn + (size_t)b * C_ * C_ +
                                  (size_t)(by * 128) * C_);
  const char* Bgb = (const char*)(wot + (size_t)(bx * 128) * C_);
  ZERO_ACC(acc);
  mainloop2<C_ * 2, C_ * 2, 8>(Agb, Bgb, Als, Bls, acc);

  const int lane = threadIdx.x & 63, wv = threadIdx.x >> 6;
  const int wr = wv >> 1, wc = wv & 1;
  f16* base = mt + (size_t)b * C_ * C_;
  const int colbase = bx * 128 + wc * 64;
  const int rowbase = by * 128 + wr * 64;
#pragma unroll
  for (int j = 0; j < 4; ++j) {
    const int e = colbase + j * 16 + (lane & 15);
#pragma unroll
    for (int i = 0; i < 4; ++i) {
      const int c0 = rowbase + i * 16 + ((lane >> 4) << 2);
      f32x4 a = acc[i][j];
      f16x4 h = {(f16)a[0], (f16)a[1], (f16)a[2], (f16)a[3]};
      *(f16x4*)(base + (size_t)e * C_ + c0) = h;  // transposed store
    }
  }
}

// out[n][e] = sum_c v[n][c] * M[c][e] + bo[e]   (fp32 out)
// grid: 1024 = 4 col tiles x 256 row tiles, NT=8
__global__ void __launch_bounds__(256, 2)
    k_gemm_out(const f16* __restrict__ v16, const f16* __restrict__ mt,
               const float* __restrict__ bo, float* __restrict__ out) {
  __shared__ alignas(16) f16 Als[2 * 8192];
  __shared__ alignas(16) f16 Bls[2 * 8192];
  const int l = xcd_remap(blockIdx.x, 1024);
  const int bx = l & 3;
  const int my = l >> 2;                   // row tile over 32768 rows
  const int b = (my * 128) >> 12;          // uniform per block
  const char* Agb = (const char*)(v16 + (size_t)my * 128 * C_);
  const char* Bgb = (const char*)(mt + (size_t)b * C_ * C_ +
                                  (size_t)(bx * 128) * C_);
  ZERO_ACC(acc);
  mainloop2<C_ * 2, C_ * 2, 8>(Agb, Bgb, Als, Bls, acc);

  const int lane = threadIdx.x & 63, wv = threadIdx.x >> 6;
  const int wr = wv >> 1, wc = wv & 1;
#pragma unroll
  for (int n = 0; n < 4; ++n) {
    const int e = bx * 128 + wc * 64 + n * 16 + (lane & 15);
    const float bias = bo[e];
#pragma unroll
    for (int m = 0; m < 4; ++m) {
      const int rg = my * 128 + wr * 64 + m * 16 + ((lane >> 4) << 2);
#pragma unroll
      for (int r = 0; r < 4; ++r)
        out[(size_t)(rg + r) * C_ + e] = acc[m][n][r] + bias;
    }
  }
}

// ---------------------------------------------------------------------------
extern "C" void kernel_launch(void* const* d_in, const int* in_sizes, int n_in,
                              void* d_out, int out_size, void* d_ws,
                              size_t ws_size, hipStream_t stream) {
  const float* x = (const float*)d_in[0];
  const float* adj = (const float*)d_in[1];
  const float* Wqkv = (const float*)d_in[2];
  const float* bqkv = (const float*)d_in[3];
  const float* Wo = (const float*)d_in[4];
  const float* bo = (const float*)d_in[5];
  float* out = (float*)d_out;

  char* ws = (char*)d_ws;
  size_t off = 0;
  auto carve = [&](size_t bytes) -> char* {
    char* p = ws + off;
    off += (bytes + 255) & ~(size_t)255;
    return p;
  };
  f16* x16 = (f16*)carve((size_t)B_ * N_ * C_ * 2);       // 33.6 MB
  f16* wqkvt = (f16*)carve((size_t)3 * C_ * C_ * 2);      // 1.6 MB
  f16* wot = (f16*)carve((size_t)C_ * C_ * 2);            // 0.5 MB
  f16* q_t = (f16*)carve((size_t)B_ * C_ * N_ * 2);       // 33.6 MB
  f16* k_t = (f16*)carve((size_t)B_ * C_ * N_ * 2);       // 33.6 MB
  f16* v16 = (f16*)carve((size_t)B_ * N_ * C_ * 2);       // 33.6 MB
  // aliases over dead buffers (stream order guarantees liveness separation)
  f16* spart = x16;             // 4 splits x 8 x 512 x 512 f16 = 16.8 MB
  f16* attn16 = k_t;            // 4.2 MB, k_t dead after scores
  f16* mt16 = q_t;              // 4.2 MB, q_t dead after scores

  k_prep<<<20480, 256, 0, stream>>>(x, Wqkv, Wo, x16, wqkvt, wot);
  k_gemm_qkv<<<3072, 256, 0, stream>>>(x16, wqkvt, bqkv, q_t, k_t, v16);
  k_gemm_scores<<<512, 256, 0, stream>>>(q_t, k_t, spart);
  k_softmax_gate<<<1024, 256, 0, stream>>>(spart, adj, attn16);
  k_gemm_m<<<128, 256, 0, stream>>>(attn16, wot, mt16);
  k_gemm_out<<<1024, 256, 0, stream>>>(v16, mt16, bo, out);
}